// Round 1
// baseline (164.076 us; speedup 1.0000x reference)
//
#include <hip/hip_runtime.h>

// Regime-switching Kalman filter, structure-exploiting scalar form.
// Per-series effective state: prob(2), eta1(3), P1(3x3 sym = 6), m2(1), p2(1).

static __device__ __forceinline__ float frcp(float x) { return __builtin_amdgcn_rcpf(x); }

#define NLOG2PI    16.540893597684108f   // 9*log(2*pi)
#define LOG_1M_P22 -9.210330372026184f   // log(1 - 0.9999 + 1e-9), f64-evaluated like the reference
#define LOG_P22    -1.00004000233e-4f    // log(0.9999 + 1e-9)
#define EPSF       1e-9f

__global__ void transpose_k(const float* __restrict__ in, float* __restrict__ out, int R, int C)
{
    __shared__ float tile[32][33];
    int c0 = blockIdx.x * 32, r0 = blockIdx.y * 32;
    int tx = threadIdx.x, ty = threadIdx.y;
    #pragma unroll
    for (int i = ty; i < 32; i += 8) {
        int r = r0 + i, c = c0 + tx;
        if (r < R && c < C) tile[i][tx] = in[(size_t)r * C + c];
    }
    __syncthreads();
    #pragma unroll
    for (int i = ty; i < 32; i += 8) {
        int c = c0 + i, r = r0 + tx;
        if (r < R && c < C) out[(size_t)c * R + r] = tile[tx][i];
    }
}

template <bool TR>
__global__ __launch_bounds__(64)
void kf_kernel(const float* __restrict__ y,      // TR: yT[t][o][n]   else: y[n][t][o]
               const float* __restrict__ pBG, const float* __restrict__ pBT,
               const float* __restrict__ pBB, const float* __restrict__ pBW,
               const float* __restrict__ lam1, const float* __restrict__ lam2,
               const float* __restrict__ qd,  const float* __restrict__ rd,
               const float* __restrict__ pG1, const float* __restrict__ pG2,
               float* __restrict__ out, int N, int Nt)
{
    const int n = blockIdx.x * 64 + threadIdx.x;
    float acc = 0.0f;
    if (n < N) {
        const float bg = pBG[0], bt = pBT[0], bb = pBB[0], bw = pBW[0];
        float a[9], l2v[9], id[9], ad[9], ld[9];
        a[0] = 1.f; a[1] = lam1[0]; a[2] = lam1[1];
        a[3] = 1.f; a[4] = lam1[2]; a[5] = lam1[3];
        a[6] = 1.f; a[7] = lam1[4]; a[8] = lam1[5];
        l2v[0] = 1.f;
        #pragma unroll
        for (int i = 0; i < 8; ++i) l2v[i + 1] = lam2[i];
        float logdetD = 0.f;
        #pragma unroll
        for (int o = 0; o < 9; ++o) {
            float dv = fabsf(rd[o]) + 1.0e-4f + 1.0e-5f;  // R diag + jitter
            id[o] = 1.0f / dv;
            ad[o] = a[o] * id[o];
            ld[o] = l2v[o] * id[o];
            logdetD += __logf(dv);
        }
        const float q0 = fabsf(qd[0]) + 1e-4f, q1 = fabsf(qd[1]) + 1e-4f;
        const float q2 = fabsf(qd[2]) + 1e-4f, q3 = fabsf(qd[3]) + 1e-4f;
        const float g0 = a[0]*ad[0] + a[1]*ad[1] + a[2]*ad[2];   // A^T D^-1 A (diagonal)
        const float g1 = a[3]*ad[3] + a[4]*ad[4] + a[5]*ad[5];
        const float g2 = a[6]*ad[6] + a[7]*ad[7] + a[8]*ad[8];
        float h = 0.f;
        #pragma unroll
        for (int o = 0; o < 9; ++o) h += l2v[o] * ld[o];         // l2^T D^-1 l2
        // branch-12 constants (prior N(0, diag(q0..q2)))
        const float pk0 = q0 / (1.f + q0 * g0);
        const float pk1 = q1 / (1.f + q1 * g1);
        const float pk2 = q2 / (1.f + q2 * g2);
        const float logdet12 = logdetD + __logf((1.f + q0*g0) * (1.f + q1*g1) * (1.f + q2*g2));
        const float gam1 = pG1[0], w0 = pG2[0], w1 = pG2[1], w2 = pG2[2];

        // ---- state ----
        float pr1 = 0.99f, pr2 = 0.01f;
        float se0 = 0.f, se1 = 0.f, se2 = 0.f;                 // eta1[0..2] (eta1[3]==0 always)
        float P00 = 1000.f, P01 = 0.f, P02 = 0.f, P11 = 1000.f, P12 = 0.f, P22 = 1000.f;
        float sm2 = 0.f, sp2 = 1e-9f;                           // eta2[3], P2[3][3]

        // prefetch t=0
        float yn[9];
        #pragma unroll
        for (int o = 0; o < 9; ++o)
            yn[o] = TR ? y[(size_t)o * N + n] : y[(size_t)n * Nt * 9 + o];

        for (int t = 0; t < Nt; ++t) {
            float yv[9];
            #pragma unroll
            for (int o = 0; o < 9; ++o) yv[o] = yn[o];
            if (t + 1 < Nt) {
                #pragma unroll
                for (int o = 0; o < 9; ++o)
                    yn[o] = TR ? y[((size_t)(t + 1) * 9 + o) * N + n]
                               : y[(size_t)n * Nt * 9 + (size_t)(t + 1) * 9 + o];
            }
            // HMM transition prob
            float logit = gam1 + w0 * se0 + w1 * se1 + w2 * se2;
            float p11tr = frcp(1.0f + __expf(-logit));

            // ---------- branch 11 (regime1 -> regime1), rank-3 Woodbury ----------
            float ep0 = bg * se0, ep1 = bt * se1, ep2 = bb * se2;
            float S00 = bg*bg*P00 + q0, S01 = bg*bt*P01, S02 = bg*bb*P02;
            float S11 = bt*bt*P11 + q1, S12 = bt*bb*P12, S22 = bb*bb*P22 + q2;
            float v0 = yv[0] - a[0]*ep0, v1 = yv[1] - a[1]*ep0, v2 = yv[2] - a[2]*ep0;
            float v3 = yv[3] - a[3]*ep1, v4 = yv[4] - a[4]*ep1, v5 = yv[5] - a[5]*ep1;
            float v6 = yv[6] - a[6]*ep2, v7 = yv[7] - a[7]*ep2, v8 = yv[8] - a[8]*ep2;
            float u0 = ad[0]*v0 + ad[1]*v1 + ad[2]*v2;
            float u1 = ad[3]*v3 + ad[4]*v4 + ad[5]*v5;
            float u2 = ad[6]*v6 + ad[7]*v7 + ad[8]*v8;
            float vdv = id[0]*v0*v0 + id[1]*v1*v1 + id[2]*v2*v2
                      + id[3]*v3*v3 + id[4]*v4*v4 + id[5]*v5*v5
                      + id[6]*v6*v6 + id[7]*v7*v7 + id[8]*v8*v8;
            // S^{-1} via adjugate
            float cA = S11*S22 - S12*S12, cB = S02*S12 - S01*S22, cC = S01*S12 - S02*S11;
            float detS = S00*cA + S01*cB + S02*cC;
            float cD = S00*S22 - S02*S02, cE = S01*S02 - S00*S12, cF = S00*S11 - S01*S01;
            float iS = frcp(detS);
            float C00 = cA*iS + g0, C01 = cB*iS, C02 = cC*iS;
            float C11 = cD*iS + g1, C12 = cE*iS, C22 = cF*iS + g2;
            float eA = C11*C22 - C12*C12, eB = C02*C12 - C01*C22, eC = C01*C12 - C02*C11;
            float detC = C00*eA + C01*eB + C02*eC;
            float eD = C00*C22 - C02*C02, eE = C01*C02 - C00*C12, eF = C00*C11 - C01*C01;
            float iC = frcp(detC);
            float Ci00 = eA*iC, Ci01 = eB*iC, Ci02 = eC*iC;   // posterior cov (=C^{-1})
            float Ci11 = eD*iC, Ci12 = eE*iC, Ci22 = eF*iC;
            float t0 = Ci00*u0 + Ci01*u1 + Ci02*u2;
            float t1 = Ci01*u0 + Ci11*u1 + Ci12*u2;
            float t2 = Ci02*u0 + Ci12*u1 + Ci22*u2;
            float quad11 = vdv - (u0*t0 + u1*t1 + u2*t2);
            float ll11 = -0.5f * (quad11 + logdetD + __logf(detS * detC) + NLOG2PI);
            float eu0 = ep0 + t0, eu1 = ep1 + t1, eu2 = ep2 + t2;

            // ---------- branch 12 (regime2 -> regime1), constant prior ----------
            float u120 = u0 + g0*ep0, u121 = u1 + g1*ep1, u122 = u2 + g2*ep2;  // A^T D^-1 y
            float ydy = vdv + 2.f*(ep0*u0 + ep1*u1 + ep2*u2)
                      + g0*ep0*ep0 + g1*ep1*ep1 + g2*ep2*ep2;                  // y^T D^-1 y
            float quad12 = ydy - (pk0*u120*u120 + pk1*u121*u121 + pk2*u122*u122);
            float ll12 = -0.5f * (quad12 + logdet12 + NLOG2PI);
            float f0 = pk0*u120, f1 = pk1*u121, f2 = pk2*u122;                 // eu12

            // ---------- branches 21/22 (-> regime2), rank-1 Sherman-Morrison ----------
            float yl = ld[0]*yv[0] + ld[1]*yv[1] + ld[2]*yv[2] + ld[3]*yv[3] + ld[4]*yv[4]
                     + ld[5]*yv[5] + ld[6]*yv[6] + ld[7]*yv[7] + ld[8]*yv[8];  // l2^T D^-1 y
            float m21 = (se0 + se1 + se2) * (1.0f / 3.0f);
            float sP = P00 + P11 + P22 + 2.f*(P01 + P02 + P12);
            float pa = q3 + (1.0f / 9.0f) * sP;          // Pp21[3,3]
            float m22 = bw * sm2;
            float pb = bw*bw*sp2 + q3;                   // Pp22[3,3]
            // 21
            float u1a = yl - m21*h;
            float vda = ydy - m21*(2.f*yl - m21*h);
            float dena = 1.f + pa*h;  float idea = frcp(dena);
            float quad21 = vda - pa*u1a*u1a*idea;
            float ll21 = -0.5f * (quad21 + logdetD + __logf(dena) + NLOG2PI);
            float pua = pa*idea;
            float eua = m21 + pua*u1a;
            // 22
            float u1b = yl - m22*h;
            float vdb = ydy - m22*(2.f*yl - m22*h);
            float denb = 1.f + pb*h;  float ideb = frcp(denb);
            float quad22 = vdb - pb*u1b*u1b*ideb;
            float ll22 = -0.5f * (quad22 + logdetD + __logf(denb) + NLOG2PI);
            float pub = pb*ideb;
            float eub = m22 + pub*u1b;

            // ---------- mixing ----------
            float lp1 = __logf(pr1 + EPSF), lp2 = __logf(pr2 + EPSF);
            float c11 = lp1 + __logf(p11tr + EPSF) + ll11;
            float c21 = lp1 + __logf(1.0f - p11tr + EPSF) + ll21;
            float c12 = lp2 + LOG_1M_P22 + ll12;
            float c22 = lp2 + LOG_P22 + ll22;
            float mx = fmaxf(fmaxf(c11, c12), fmaxf(c21, c22));
            float s11 = __expf(c11 - mx), s12 = __expf(c12 - mx);
            float s21 = __expf(c21 - mx), s22 = __expf(c22 - mx);
            float ssum = s11 + s12 + s21 + s22;
            acc += mx + __logf(ssum);
            float pr1n = s11 + s12, pr2n = s21 + s22;
            float inv1 = frcp(pr1n + EPSF * ssum);
            float W11 = s11 * inv1, W12 = s12 * inv1;
            float inv2 = frcp(pr2n + EPSF * ssum);
            float W21 = s21 * inv2, W22 = s22 * inv2;
            float issum = frcp(ssum);
            pr1 = pr1n * issum; pr2 = pr2n * issum;

            // ---------- collapse regime 1 (3x3) ----------
            float ne0 = W11*eu0 + W12*f0;
            float ne1 = W11*eu1 + W12*f1;
            float ne2 = W11*eu2 + W12*f2;
            float da0 = eu0 - ne0, da1 = eu1 - ne1, da2 = eu2 - ne2;
            float db0 = f0 - ne0,  db1 = f1 - ne1,  db2 = f2 - ne2;
            P00 = W11*(Ci00 + da0*da0) + W12*(pk0 + db0*db0);
            P01 = W11*(Ci01 + da0*da1) + W12*(db0*db1);
            P02 = W11*(Ci02 + da0*da2) + W12*(db0*db2);
            P11 = W11*(Ci11 + da1*da1) + W12*(pk1 + db1*db1);
            P12 = W11*(Ci12 + da1*da2) + W12*(db1*db2);
            P22 = W11*(Ci22 + da2*da2) + W12*(pk2 + db2*db2);
            se0 = ne0; se1 = ne1; se2 = ne2;

            // ---------- collapse regime 2 (scalar) ----------
            float nm2 = W21*eua + W22*eub;
            float dc = eua - nm2, dd = eub - nm2;
            sp2 = W21*(pua + dc*dc) + W22*(pub + dd*dd);
            sm2 = nm2;
        }
    }
    // wave (=block) reduction, then one atomic per block
    #pragma unroll
    for (int off = 32; off; off >>= 1) acc += __shfl_down(acc, off, 64);
    if (threadIdx.x == 0) atomicAdd(out, acc);
}

extern "C" void kernel_launch(void* const* d_in, const int* in_sizes, int n_in,
                              void* d_out, int out_size, void* d_ws, size_t ws_size,
                              hipStream_t stream)
{
    const float* y    = (const float*)d_in[0];
    const float* pBG  = (const float*)d_in[1];
    const float* pBT  = (const float*)d_in[2];
    const float* pBB  = (const float*)d_in[3];
    const float* pBW  = (const float*)d_in[4];
    const float* lam1 = (const float*)d_in[5];
    const float* lam2 = (const float*)d_in[6];
    const float* qd   = (const float*)d_in[7];
    const float* rd   = (const float*)d_in[8];
    const float* pG1  = (const float*)d_in[9];
    const float* pG2  = (const float*)d_in[10];

    const int total = in_sizes[0];
    const int Nt = 64, O = 9;
    const int N = total / (Nt * O);

    hipMemsetAsync(d_out, 0, sizeof(float) * (size_t)out_size, stream);

    const size_t need = (size_t)total * sizeof(float);
    const int blocks = (N + 63) / 64;
    if (ws_size >= need) {
        float* yT = (float*)d_ws;
        dim3 tb(32, 8);
        dim3 tg((Nt * O + 31) / 32, (N + 31) / 32);
        transpose_k<<<tg, tb, 0, stream>>>(y, yT, N, Nt * O);
        kf_kernel<true><<<blocks, 64, 0, stream>>>(yT, pBG, pBT, pBB, pBW, lam1, lam2,
                                                   qd, rd, pG1, pG2, (float*)d_out, N, Nt);
    } else {
        kf_kernel<false><<<blocks, 64, 0, stream>>>(y, pBG, pBT, pBB, pBW, lam1, lam2,
                                                    qd, rd, pG1, pG2, (float*)d_out, N, Nt);
    }
}